// Round 1
// baseline (60.957 us; speedup 1.0000x reference)
//
#include <hip/hip_runtime.h>

#define H  4096
#define W  8192
#define KH 3
#define KW 3
#define HO (H - KH + 1)   // 4094
#define WO (W - KW + 1)   // 8190
#define RPT 4             // output rows per thread
#define CPT 4             // output cols per thread
#define BLK 256

__global__ __launch_bounds__(BLK) void ConvLayer_4140348473931_kernel(
    const float* __restrict__ X, const float* __restrict__ Wt,
    const float* __restrict__ Bias, float* __restrict__ Out)
{
    const int tid = threadIdx.x;
    const int c0 = blockIdx.x * (BLK * CPT) + tid * CPT;   // multiple of 4
    const int r0 = blockIdx.y * RPT;

    // uniform weights + bias (scalar-cached)
    float w[9];
#pragma unroll
    for (int i = 0; i < 9; ++i) w[i] = Wt[i];
    const float bias = Bias[0];

    float x[RPT + 2][CPT + 2];

    if (c0 + CPT + 2 <= W) {
        // fast path: float4 + float2 per input row (16B-aligned: c0 % 4 == 0)
#pragma unroll
        for (int ir = 0; ir < RPT + 2; ++ir) {
            int r = r0 + ir; if (r > H - 1) r = H - 1;   // clamped rows feed only masked outputs
            const float* row = X + (size_t)r * W + c0;
            float4 v  = *reinterpret_cast<const float4*>(row);
            float2 v2 = *reinterpret_cast<const float2*>(row + 4);
            x[ir][0] = v.x;  x[ir][1] = v.y;  x[ir][2] = v.z;  x[ir][3] = v.w;
            x[ir][4] = v2.x; x[ir][5] = v2.y;
        }
    } else {
        // right-edge: guarded scalar loads (one thread per row-strip)
#pragma unroll
        for (int ir = 0; ir < RPT + 2; ++ir) {
            int r = r0 + ir; if (r > H - 1) r = H - 1;
            const float* row = X + (size_t)r * W;
#pragma unroll
            for (int jc = 0; jc < CPT + 2; ++jc) {
                int c = c0 + jc; if (c > W - 1) c = W - 1;
                x[ir][jc] = row[c];
            }
        }
    }

    float acc[RPT][CPT];
#pragma unroll
    for (int i = 0; i < RPT; ++i) {
#pragma unroll
        for (int j = 0; j < CPT; ++j) {
            float s = bias;
#pragma unroll
            for (int kh = 0; kh < KH; ++kh)
#pragma unroll
                for (int kw = 0; kw < KW; ++kw)
                    s = fmaf(w[kh * 3 + kw], x[i + kh][j + kw], s);
            acc[i][j] = s;
        }
    }

    if (c0 + CPT <= WO) {
        // float2 stores: out row offset r*8190 + c0 is always even -> 8B aligned
#pragma unroll
        for (int i = 0; i < RPT; ++i) {
            int r = r0 + i;
            if (r < HO) {
                float* orow = Out + (size_t)r * WO + c0;
                *reinterpret_cast<float2*>(orow)     = make_float2(acc[i][0], acc[i][1]);
                *reinterpret_cast<float2*>(orow + 2) = make_float2(acc[i][2], acc[i][3]);
            }
        }
    } else {
#pragma unroll
        for (int i = 0; i < RPT; ++i) {
            int r = r0 + i;
            if (r < HO) {
#pragma unroll
                for (int j = 0; j < CPT; ++j) {
                    int c = c0 + j;
                    if (c < WO) Out[(size_t)r * WO + c] = acc[i][j];
                }
            }
        }
    }
}

extern "C" void kernel_launch(void* const* d_in, const int* in_sizes, int n_in,
                              void* d_out, int out_size, void* d_ws, size_t ws_size,
                              hipStream_t stream) {
    const float* X    = (const float*)d_in[0];
    const float* Wt   = (const float*)d_in[1];
    const float* Bias = (const float*)d_in[2];
    float* Out        = (float*)d_out;

    dim3 block(BLK);
    dim3 grid((WO + BLK * CPT - 1) / (BLK * CPT),   // 8
              (HO + RPT - 1) / RPT);                // 1024
    ConvLayer_4140348473931_kernel<<<grid, block, 0, stream>>>(X, Wt, Bias, Out);
}

// Round 3
// 60.243 us; speedup vs baseline: 1.0118x; 1.0118x over previous
//
#include <hip/hip_runtime.h>

#define H  4096
#define W  8192
#define KH 3
#define KW 3
#define HO (H - KH + 1)   // 4094
#define WO (W - KW + 1)   // 8190
#define RPT 4             // output rows per thread
#define CPT 4             // output cols per thread
#define BLK 256

typedef float vfloat2 __attribute__((ext_vector_type(2)));

__global__ __launch_bounds__(BLK) void ConvLayer_4140348473931_kernel(
    const float* __restrict__ X, const float* __restrict__ Wt,
    const float* __restrict__ Bias, float* __restrict__ Out)
{
    const int tid = threadIdx.x;
    const int c0 = blockIdx.x * (BLK * CPT) + tid * CPT;   // multiple of 4
    const int r0 = blockIdx.y * RPT;

    // uniform weights + bias (scalar-cached)
    float w[9];
#pragma unroll
    for (int i = 0; i < 9; ++i) w[i] = Wt[i];
    const float bias = Bias[0];

    float x[RPT + 2][CPT + 2];

    if (c0 + CPT + 2 <= W) {
        // fast path: float4 + float2 per input row (16B-aligned: c0 % 4 == 0)
#pragma unroll
        for (int ir = 0; ir < RPT + 2; ++ir) {
            int r = r0 + ir; if (r > H - 1) r = H - 1;   // clamped rows feed only masked outputs
            const float* row = X + (size_t)r * W + c0;
            float4 v  = *reinterpret_cast<const float4*>(row);
            float2 v2 = *reinterpret_cast<const float2*>(row + 4);
            x[ir][0] = v.x;  x[ir][1] = v.y;  x[ir][2] = v.z;  x[ir][3] = v.w;
            x[ir][4] = v2.x; x[ir][5] = v2.y;
        }
    } else {
        // right-edge: guarded scalar loads (one thread per row-strip)
#pragma unroll
        for (int ir = 0; ir < RPT + 2; ++ir) {
            int r = r0 + ir; if (r > H - 1) r = H - 1;
            const float* row = X + (size_t)r * W;
#pragma unroll
            for (int jc = 0; jc < CPT + 2; ++jc) {
                int c = c0 + jc; if (c > W - 1) c = W - 1;
                x[ir][jc] = row[c];
            }
        }
    }

    float acc[RPT][CPT];
#pragma unroll
    for (int i = 0; i < RPT; ++i) {
#pragma unroll
        for (int j = 0; j < CPT; ++j) {
            float s = bias;
#pragma unroll
            for (int kh = 0; kh < KH; ++kh)
#pragma unroll
                for (int kw = 0; kw < KW; ++kw)
                    s = fmaf(w[kh * 3 + kw], x[i + kh][j + kw], s);
            acc[i][j] = s;
        }
    }

    if (c0 + CPT <= WO) {
        // non-temporal float2 stores: output is write-once stream; bypass cache so
        // the 128 MiB input stays L3-resident (out row offset always even -> 8B aligned)
#pragma unroll
        for (int i = 0; i < RPT; ++i) {
            int r = r0 + i;
            if (r < HO) {
                float* orow = Out + (size_t)r * WO + c0;
                vfloat2 lo = {acc[i][0], acc[i][1]};
                vfloat2 hi = {acc[i][2], acc[i][3]};
                __builtin_nontemporal_store(lo, reinterpret_cast<vfloat2*>(orow));
                __builtin_nontemporal_store(hi, reinterpret_cast<vfloat2*>(orow + 2));
            }
        }
    } else {
#pragma unroll
        for (int i = 0; i < RPT; ++i) {
            int r = r0 + i;
            if (r < HO) {
#pragma unroll
                for (int j = 0; j < CPT; ++j) {
                    int c = c0 + j;
                    if (c < WO)
                        __builtin_nontemporal_store(acc[i][j], &Out[(size_t)r * WO + c]);
                }
            }
        }
    }
}

extern "C" void kernel_launch(void* const* d_in, const int* in_sizes, int n_in,
                              void* d_out, int out_size, void* d_ws, size_t ws_size,
                              hipStream_t stream) {
    const float* X    = (const float*)d_in[0];
    const float* Wt   = (const float*)d_in[1];
    const float* Bias = (const float*)d_in[2];
    float* Out        = (float*)d_out;

    dim3 block(BLK);
    dim3 grid((WO + BLK * CPT - 1) / (BLK * CPT),   // 8
              (HO + RPT - 1) / RPT);                // 1024
    ConvLayer_4140348473931_kernel<<<grid, block, 0, stream>>>(X, Wt, Bias, Out);
}

// Round 4
// 48.868 us; speedup vs baseline: 1.2474x; 1.2328x over previous
//
#include <hip/hip_runtime.h>

#define H  4096
#define W  8192
#define KH 3
#define KW 3
#define HO (H - KH + 1)   // 4094
#define WO (W - KW + 1)   // 8190
#define CPT 4             // output cols per thread
#define RPS 4             // output rows per strip
#define SPB 4             // strips per block band
#define BAND (RPS * SPB)  // 16 output rows per block
#define BLK 256

__global__ __launch_bounds__(BLK) void ConvLayer_4140348473931_kernel(
    const float* __restrict__ X, const float* __restrict__ Wt,
    const float* __restrict__ Bias, float* __restrict__ Out)
{
    const int tid   = threadIdx.x;
    const int c0    = blockIdx.x * (BLK * CPT) + tid * CPT;  // multiple of 4
    const int rbase = blockIdx.y * BAND;
    // clamped column for the boundary float2 (last thread c0=8188 would read col 8192;
    // clamp to W-2 — the wrong values feed only outputs >= WO which are masked)
    const int cext  = min(c0 + 4, W - 2);

    float w[9];
#pragma unroll
    for (int i = 0; i < 9; ++i) w[i] = Wt[i];
    const float bias = Bias[0];

    float x[RPS + 2][6];   // rolling window: 6 input rows x 6 cols
    float pre[RPS][6];     // prefetch buffer for next strip's 4 new rows

#define LOADROW(rr, dst)                                                     \
    do {                                                                     \
        int _r = (rr); if (_r > H - 1) _r = H - 1;                           \
        const float* _row = X + (size_t)_r * W;                              \
        float4 _v  = *reinterpret_cast<const float4*>(_row + c0);            \
        float2 _v2 = *reinterpret_cast<const float2*>(_row + cext);         \
        (dst)[0] = _v.x;  (dst)[1] = _v.y;  (dst)[2] = _v.z;                 \
        (dst)[3] = _v.w;  (dst)[4] = _v2.x; (dst)[5] = _v2.y;               \
    } while (0)

    // initial fill: 6 rows of strip 0
#pragma unroll
    for (int ir = 0; ir < 6; ++ir) LOADROW(rbase + ir, x[ir]);

#pragma unroll
    for (int s = 0; s < SPB; ++s) {
        // issue next strip's loads BEFORE computing this strip (overlap)
        if (s < SPB - 1) {
#pragma unroll
            for (int ir = 0; ir < RPS; ++ir)
                LOADROW(rbase + s * RPS + 6 + ir, pre[ir]);
        }

        // compute 4x4 outputs from the rolling window
        float acc[RPS][CPT];
#pragma unroll
        for (int i = 0; i < RPS; ++i) {
#pragma unroll
            for (int j = 0; j < CPT; ++j) {
                float ss = bias;
#pragma unroll
                for (int kh = 0; kh < KH; ++kh)
#pragma unroll
                    for (int kw = 0; kw < KW; ++kw)
                        ss = fmaf(w[kh * 3 + kw], x[i + kh][j + kw], ss);
                acc[i][j] = ss;
            }
        }

        // store: float2 pairs; out row offset r*8190 + c0 always even -> 8B aligned
        {
            const int r0 = rbase + s * RPS;
            const bool full = (c0 + CPT <= WO);   // false only for the last thread (c0=8188)
#pragma unroll
            for (int i = 0; i < RPS; ++i) {
                int r = r0 + i;
                if (r < HO) {
                    float* orow = Out + (size_t)r * WO + c0;
                    *reinterpret_cast<float2*>(orow) = make_float2(acc[i][0], acc[i][1]);
                    if (full)
                        *reinterpret_cast<float2*>(orow + 2) = make_float2(acc[i][2], acc[i][3]);
                }
            }
        }

        // shift window: rows 4,5 -> 0,1 ; prefetched 4 rows -> 2..5
        if (s < SPB - 1) {
#pragma unroll
            for (int j = 0; j < 6; ++j) { x[0][j] = x[4][j]; x[1][j] = x[5][j]; }
#pragma unroll
            for (int ir = 0; ir < RPS; ++ir)
#pragma unroll
                for (int j = 0; j < 6; ++j) x[2 + ir][j] = pre[ir][j];
        }
    }
#undef LOADROW
}

extern "C" void kernel_launch(void* const* d_in, const int* in_sizes, int n_in,
                              void* d_out, int out_size, void* d_ws, size_t ws_size,
                              hipStream_t stream) {
    const float* X    = (const float*)d_in[0];
    const float* Wt   = (const float*)d_in[1];
    const float* Bias = (const float*)d_in[2];
    float* Out        = (float*)d_out;

    dim3 block(BLK);
    dim3 grid((WO + BLK * CPT - 1) / (BLK * CPT),   // 8  -> XCD = bx (column strip per XCD)
              (HO + BAND - 1) / BAND);              // 256
    ConvLayer_4140348473931_kernel<<<grid, block, 0, stream>>>(X, Wt, Bias, Out);
}

// Round 5
// 47.820 us; speedup vs baseline: 1.2747x; 1.0219x over previous
//
#include <hip/hip_runtime.h>

#define H  4096
#define W  8192
#define KH 3
#define KW 3
#define HO (H - KH + 1)   // 4094
#define WO (W - KW + 1)   // 8190
#define CPT 4             // output cols per thread
#define RPS 4             // output rows per strip
#define SPB 8             // strips per block band
#define BAND (RPS * SPB)  // 32 output rows per block
#define BLK 256

__global__ __launch_bounds__(BLK, 4) void ConvLayer_4140348473931_kernel(
    const float* __restrict__ X, const float* __restrict__ Wt,
    const float* __restrict__ Bias, float* __restrict__ Out)
{
    const int tid   = threadIdx.x;
    const int c0    = blockIdx.x * (BLK * CPT) + tid * CPT;  // multiple of 4
    const int rbase = blockIdx.y * BAND;
    // last thread (c0=8188) would read cols 8192/8193; clamp the float2 to W-2.
    // Wrong lanes feed only outputs >= WO which are masked.
    const int cext  = min(c0 + 4, W - 2);

    float w[9];
#pragma unroll
    for (int i = 0; i < 9; ++i) w[i] = Wt[i];
    const float bias = Bias[0];

    float x[6][6];      // rolling window: 6 input rows x 6 cols
    float preA[4][6];   // prefetch ping
    float preB[4][6];   // prefetch pong

#define LOADROW(rr, dst)                                                     \
    do {                                                                     \
        int _r = (rr); if (_r > H - 1) _r = H - 1;                           \
        const float* _row = X + (size_t)_r * W;                              \
        float4 _v  = *reinterpret_cast<const float4*>(_row + c0);            \
        float2 _v2 = *reinterpret_cast<const float2*>(_row + cext);          \
        (dst)[0] = _v.x;  (dst)[1] = _v.y;  (dst)[2] = _v.z;                 \
        (dst)[3] = _v.w;  (dst)[4] = _v2.x; (dst)[5] = _v2.y;                \
    } while (0)

    // prefetch for strip t loads its 4 NEW rows: rbase + t*RPS + 2 .. +5
#define PREFETCH(t, buf)                                                     \
    do {                                                                     \
        if ((t) < SPB) {                                                     \
            _Pragma("unroll")                                                \
            for (int _ir = 0; _ir < RPS; ++_ir)                              \
                LOADROW(rbase + (t) * RPS + 2 + _ir, (buf)[_ir]);            \
        }                                                                    \
    } while (0)

#define COMPUTE_STORE(s)                                                     \
    do {                                                                     \
        float acc[RPS][CPT];                                                 \
        _Pragma("unroll")                                                    \
        for (int _i = 0; _i < RPS; ++_i) {                                   \
            _Pragma("unroll")                                                \
            for (int _j = 0; _j < CPT; ++_j) {                               \
                float _s = bias;                                             \
                _Pragma("unroll")                                            \
                for (int _kh = 0; _kh < KH; ++_kh)                           \
                    _Pragma("unroll")                                        \
                    for (int _kw = 0; _kw < KW; ++_kw)                       \
                        _s = fmaf(w[_kh * 3 + _kw], x[_i + _kh][_j + _kw], _s); \
                acc[_i][_j] = _s;                                            \
            }                                                                \
        }                                                                    \
        const int _r0 = rbase + (s) * RPS;                                   \
        const bool _full = (c0 + CPT <= WO);                                 \
        _Pragma("unroll")                                                    \
        for (int _i = 0; _i < RPS; ++_i) {                                   \
            int _r = _r0 + _i;                                               \
            if (_r < HO) {                                                   \
                float* _orow = Out + (size_t)_r * WO + c0;                   \
                *reinterpret_cast<float2*>(_orow) = make_float2(acc[_i][0], acc[_i][1]); \
                if (_full)                                                   \
                    *reinterpret_cast<float2*>(_orow + 2) = make_float2(acc[_i][2], acc[_i][3]); \
            }                                                                \
        }                                                                    \
    } while (0)

#define SHIFT_FROM(buf)                                                      \
    do {                                                                     \
        _Pragma("unroll")                                                    \
        for (int _j = 0; _j < 6; ++_j) { x[0][_j] = x[4][_j]; x[1][_j] = x[5][_j]; } \
        _Pragma("unroll")                                                    \
        for (int _ir = 0; _ir < RPS; ++_ir)                                  \
            _Pragma("unroll")                                                \
            for (int _j = 0; _j < 6; ++_j) x[2 + _ir][_j] = (buf)[_ir][_j];  \
    } while (0)

    // pipeline fill: strip 0 window + strip 1's new rows
#pragma unroll
    for (int ir = 0; ir < 6; ++ir) LOADROW(rbase + ir, x[ir]);
    PREFETCH(1, preA);

    // main loop, strips in pairs so preA/preB roles are static (no runtime idx)
#pragma unroll
    for (int p = 0; p < SPB / 2; ++p) {
        const int s0 = 2 * p;
        PREFETCH(s0 + 2, preB);       // 2-deep: issue strip s0+2 loads now
        COMPUTE_STORE(s0);
        SHIFT_FROM(preA);             // waits on preA (issued 2 strips ago)

        PREFETCH(s0 + 3, preA);       // issue strip s0+3 loads
        COMPUTE_STORE(s0 + 1);
        if (s0 + 2 < SPB) SHIFT_FROM(preB);
    }

#undef LOADROW
#undef PREFETCH
#undef COMPUTE_STORE
#undef SHIFT_FROM
}

extern "C" void kernel_launch(void* const* d_in, const int* in_sizes, int n_in,
                              void* d_out, int out_size, void* d_ws, size_t ws_size,
                              hipStream_t stream) {
    const float* X    = (const float*)d_in[0];
    const float* Wt   = (const float*)d_in[1];
    const float* Bias = (const float*)d_in[2];
    float* Out        = (float*)d_out;

    dim3 block(BLK);
    dim3 grid((WO + BLK * CPT - 1) / (BLK * CPT),   // 8  -> XCD = bx (column stripe per XCD)
              (HO + BAND - 1) / BAND);              // 128
    ConvLayer_4140348473931_kernel<<<grid, block, 0, stream>>>(X, Wt, Bias, Out);
}